// Round 4
// baseline (2288.977 us; speedup 1.0000x reference)
//
#include <hip/hip_runtime.h>

// Custom LSTM scan.  B=64, L=512, P=64, A=16, D=512, F=80.
//   h_t = h_{t-1} + tanh(x_t W_ci + b_ci) * sigmoid(h_{t-1} R_ig + b_ig)
// One WG (512 thr) per batch row.  Output d computed by 8 lanes (k-slices
// of 64) reduced via DPP.  R_ig as f16 pairs: 32 uint4 chunks pinned in
// VGPRs (opaque-asm trick), 7 in LDS, 25 streamed from L2 per step.
// h broadcast as packed f16 in LDS with bank-swizzled layout.

#define B_  64
#define L_  512
#define P_  64
#define A_  16
#define D_  512
#define F_  80
#define CI_R 8

typedef _Float16 half2_t __attribute__((ext_vector_type(2)));

__device__ __forceinline__ float dot2(unsigned int r, unsigned int h, float acc) {
    return __builtin_amdgcn_fdot2(__builtin_bit_cast(half2_t, h),
                                  __builtin_bit_cast(half2_t, r), acc, false);
}
__device__ __forceinline__ float dot4u(uint4 r, uint4 h, float acc) {
    acc = dot2(r.x, h.x, acc);
    acc = dot2(r.y, h.y, acc);
    acc = dot2(r.z, h.z, acc);
    acc = dot2(r.w, h.w, acc);
    return acc;
}
template<int CTRL>
__device__ __forceinline__ float dpp_mov(float v) {
    return __builtin_bit_cast(float, __builtin_amdgcn_update_dpp(
        0, __builtin_bit_cast(int, v), CTRL, 0xF, 0xF, true));
}
// DPP ctrls: quad_perm(1,0,3,2)=0xB1 (xor1), quad_perm(2,3,0,1)=0x4E (xor2),
// row_half_mirror=0x141 (xor7), row_mirror=0x140 (xor15),
// row_bcast15=0x142, row_bcast31=0x143.

// Pack R_ig fp32[k][d] -> f16-pair uint chunks laid out [w][jc][l][q]:
// uint4 (w,jc,l) with j=jc>>3, c=jc&7 holds pairs p = g*32+c*4+{0..3}
// (k=2p,2p+1) of column d = w*64 + (l>>3)*8 + j, where g = l&7.
__global__ __launch_bounds__(256) void prep_kernel(const float* __restrict__ R,
                                                   unsigned int* __restrict__ Rp) {
    int id = blockIdx.x * 256 + threadIdx.x;          // 131072 uints
    int q = id & 3;
    int l = (id >> 2) & 63;
    int c = (id >> 8) & 7;
    int j = (id >> 11) & 7;
    int w = id >> 14;
    int r = l >> 3, g = l & 7;
    int d = w * 64 + r * 8 + j;
    int p = g * 32 + c * 4 + q;
    int k0 = 2 * p;
    half2_t v;
    v.x = (_Float16)R[k0 * D_ + d];
    v.y = (_Float16)R[(k0 + 1) * D_ + d];
    Rp[id] = __builtin_bit_cast(unsigned int, v);
}

// ci = tanh(x @ W_ci + b_ci), stored f16.  One block does CI_R (b,l) rows.
__global__ __launch_bounds__(256) void ci_kernel(const float* __restrict__ obs,
                                                 const float* __restrict__ act,
                                                 const float* __restrict__ W,
                                                 const float* __restrict__ bci,
                                                 unsigned short* __restrict__ ci) {
    __shared__ float xs[CI_R][F_];
    int row0 = blockIdx.x * CI_R;
    int tid = threadIdx.x;
    for (int idx = tid; idx < CI_R * F_; idx += 256) {
        int r = idx / F_, f = idx % F_;
        float v = (f < P_) ? obs[(size_t)(row0 + r) * P_ + f]
                           : act[(size_t)(row0 + r) * A_ + (f - P_)];
        xs[r][f] = v;
    }
    __syncthreads();
    int d0 = tid, d1 = tid + 256;
    float a0[CI_R], a1[CI_R];
    #pragma unroll
    for (int r = 0; r < CI_R; ++r) { a0[r] = 0.f; a1[r] = 0.f; }
    for (int f = 0; f < F_; ++f) {
        float w0 = W[f * D_ + d0];
        float w1 = W[f * D_ + d1];
        #pragma unroll
        for (int r = 0; r < CI_R; ++r) {
            float xv = xs[r][f];
            a0[r] += xv * w0;
            a1[r] += xv * w1;
        }
    }
    float b0 = bci[d0], b1 = bci[d1];
    #pragma unroll
    for (int r = 0; r < CI_R; ++r) {
        float z0 = a0[r] + b0, z1 = a1[r] + b1;
        float e0 = __expf(-2.f * __builtin_fabsf(z0));
        float e1 = __expf(-2.f * __builtin_fabsf(z1));
        float m0 = (1.f - e0) * __builtin_amdgcn_rcpf(1.f + e0);
        float m1 = (1.f - e1) * __builtin_amdgcn_rcpf(1.f + e1);
        float t0 = z0 < 0.f ? -m0 : m0;
        float t1 = z1 < 0.f ? -m1 : m1;
        ci[(size_t)(row0 + r) * D_ + d0] = __builtin_bit_cast(unsigned short, (_Float16)t0);
        ci[(size_t)(row0 + r) * D_ + d1] = __builtin_bit_cast(unsigned short, (_Float16)t1);
    }
}

// Serial scan.  One block per batch row.  Thread (w=tid>>6, l=tid&63):
// g=l&7; computes partials over k in [g*64,g*64+64) for outputs
// d = w*64 + (l>>3)*8 + j, j=0..7; DPP reduce-scatter leaves lane with
// j=g -> thread owns d = tid.  Chunks jc=j*8+c: 0..31 regs (pinned),
// 32..38 LDS, 39..63 streamed from L2 in 3 groups (A=39..47, B=48..55,
// C=56..63) through a shared 9-chunk buffer.
__global__ __launch_bounds__(512, 2) void scan_kernel(
    const uint4* __restrict__ Rp, const unsigned short* __restrict__ ci,
    const float* __restrict__ b_ig, const float* __restrict__ W_out,
    const float* __restrict__ b_out, float* __restrict__ out)
{
    const int tid = threadIdx.x;
    const int b = blockIdx.x;
    const int w = tid >> 6;
    const int l = tid & 63;
    const int g = l & 7;

    __shared__ uint4 ldsR[7 * D_];
    __shared__ __align__(16) unsigned int hp[D_ / 2];   // swizzled packed f16 h
    __shared__ float red[8];
    __shared__ float outbuf[L_];

    const uint4* tb = Rp + (w << 12) + l;   // chunk jc at tb[jc*64]

    // pin 32 chunks (jc 0..31 -> j=0..3) in VGPRs; opaque asm stops the
    // allocator from sinking these loads into the t-loop (round-3 failure:
    // VGPR_Count=128 meant everything re-streamed from L2 every step)
    uint4 rr[32];
    #pragma unroll
    for (int i = 0; i < 32; ++i) rr[i] = tb[i * 64];
    #pragma unroll
    for (int i = 0; i < 32; ++i)
        asm volatile("" : "+v"(rr[i].x), "+v"(rr[i].y), "+v"(rr[i].z), "+v"(rr[i].w));

    #pragma unroll
    for (int i = 0; i < 7; ++i) ldsR[i * D_ + tid] = tb[(32 + i) * 64];
    if (tid < 256) hp[tid] = 0u;

    float hval = 0.f;                      // h[tid], fp32, persistent
    const float bg = b_ig[tid];
    const float wo = W_out[tid];
    const float bo = b_out[0];
    const unsigned short* cip = ci + (size_t)b * L_ * D_ + tid;

    // h write slot (swizzled): pair (h[tid],h[tid+1]) -> uint u=tid>>1,
    // uint4 i=tid>>3 (g_i=w, c_i=(tid>>3)&7) -> slot=(w<<3)|((c_i+w)&7)
    const int wslot = (((w << 3) | ((((tid >> 3) & 7) + w) & 7)) << 2) | ((tid >> 1) & 3);

    __syncthreads();

    const uint4* hp4s = (const uint4*)hp;

    #pragma unroll 1
    for (int t = 0; t < L_; ++t) {
        // issue stream group A (jc 39..47) + ci load
        uint4 sb[9];
        #pragma unroll
        for (int i = 0; i < 9; ++i) sb[i] = tb[(39 + i) * 64];
        unsigned short cu = cip[t * D_];

        // h slice (8 uint4) from swizzled LDS: slot (g<<3)|((c+g)&7)
        // -> 8 distinct bank-quads across the 8 g-groups: conflict-free
        uint4 hsr[8];
        #pragma unroll
        for (int c = 0; c < 8; ++c) hsr[c] = hp4s[(g << 3) | ((c + g) & 7)];

        float p[8];
        #pragma unroll
        for (int j = 0; j < 8; ++j) p[j] = 0.f;

        // register chunks j=0,1 (covers A's L2 latency)
        #pragma unroll
        for (int i = 0; i < 16; ++i) p[i >> 3] = dot4u(rr[i], hsr[i & 7], p[i >> 3]);

        // consume A: jc39=(j4,c7); jc40..47=(j5,c0..7)
        p[4] = dot4u(sb[0], hsr[7], p[4]);
        #pragma unroll
        for (int c = 0; c < 8; ++c) p[5] = dot4u(sb[1 + c], hsr[c], p[5]);

        // issue stream group B (jc 48..55 -> j=6)
        #pragma unroll
        for (int i = 0; i < 8; ++i) sb[i] = tb[(48 + i) * 64];

        // register chunks j=2,3 (covers B's latency)
        #pragma unroll
        for (int i = 16; i < 32; ++i) p[i >> 3] = dot4u(rr[i], hsr[i & 7], p[i >> 3]);

        // consume B
        #pragma unroll
        for (int c = 0; c < 8; ++c) p[6] = dot4u(sb[c], hsr[c], p[6]);

        // issue stream group C (jc 56..63 -> j=7)
        #pragma unroll
        for (int i = 0; i < 8; ++i) sb[i] = tb[(56 + i) * 64];

        // LDS chunks jc32..38 = (j4, c0..6) (covers C's latency)
        #pragma unroll
        for (int i = 0; i < 7; ++i) p[4] = dot4u(ldsR[i * D_ + tid], hsr[i], p[4]);

        // consume C
        #pragma unroll
        for (int c = 0; c < 8; ++c) p[7] = dot4u(sb[c], hsr[c], p[7]);

        // reduce-scatter over the 8-lane slice group (all DPP):
        float q0[4];
        #pragma unroll
        for (int i = 0; i < 4; ++i) {
            float a = p[i] + dpp_mov<0x141>(p[i]);       // xor7
            float c2 = p[i + 4] + dpp_mov<0x141>(p[i + 4]);
            q0[i] = (g & 4) ? c2 : a;
        }
        float r0a = q0[0] + dpp_mov<0xB1>(q0[0]);        // xor1
        float r0b = q0[1] + dpp_mov<0xB1>(q0[1]);
        float r1a = q0[2] + dpp_mov<0xB1>(q0[2]);
        float r1b = q0[3] + dpp_mov<0xB1>(q0[3]);
        float r0 = (g & 1) ? r0b : r0a;
        float r1 = (g & 1) ? r1b : r1a;
        float za = r0 + dpp_mov<0x4E>(r0);               // xor2
        float zb = r1 + dpp_mov<0x4E>(r1);
        float z = (g & 2) ? zb : za;                     // z for d = tid

        float zz = z + bg;
        float ig = __builtin_amdgcn_rcpf(1.f + __expf(-zz));
        float civ = (float)__builtin_bit_cast(_Float16, cu);
        hval += civ * ig;

        // wave-reduce hval*wo via DPP (sum lands in lane 63)
        float po = hval * wo;
        po += dpp_mov<0xB1>(po);
        po += dpp_mov<0x4E>(po);
        po += dpp_mov<0x141>(po);
        po += dpp_mov<0x140>(po);
        po += dpp_mov<0x142>(po);
        po += dpp_mov<0x143>(po);

        float nbh = dpp_mov<0xB1>(hval);  // neighbor (lane^1) h

        __syncthreads();                  // all reads of old hp complete
        if ((tid & 1) == 0) {
            hp[wslot] = __builtin_bit_cast(unsigned int,
                            __builtin_amdgcn_cvt_pkrtz(hval, nbh));
        }
        if (l == 63) red[w] = po;
        __syncthreads();                  // new hp + partials visible
        if (tid == 0) {
            outbuf[t] = red[0] + red[1] + red[2] + red[3] +
                        red[4] + red[5] + red[6] + red[7] + bo;
        }
    }
    __syncthreads();
    out[b * L_ + tid] = outbuf[tid];
}

extern "C" void kernel_launch(void* const* d_in, const int* in_sizes, int n_in,
                              void* d_out, int out_size, void* d_ws, size_t ws_size,
                              hipStream_t stream) {
    const float* obs   = (const float*)d_in[0];
    const float* act   = (const float*)d_in[1];
    const float* W_ci  = (const float*)d_in[2];
    const float* b_ci  = (const float*)d_in[3];
    const float* R_ig  = (const float*)d_in[4];
    const float* b_ig  = (const float*)d_in[5];
    const float* W_out = (const float*)d_in[6];
    const float* b_out = (const float*)d_in[7];
    float* out = (float*)d_out;

    unsigned short* ci = (unsigned short*)d_ws;                        // 32 MB f16
    unsigned int* Rp = (unsigned int*)((char*)d_ws + (size_t)B_ * L_ * D_ * 2);

    prep_kernel<<<512, 256, 0, stream>>>(R_ig, Rp);
    ci_kernel<<<(B_ * L_) / CI_R, 256, 0, stream>>>(obs, act, W_ci, b_ci, ci);
    scan_kernel<<<B_, D_, 0, stream>>>((const uint4*)Rp, ci, b_ig, W_out, b_out, out);
}

// Round 5
// 1160.351 us; speedup vs baseline: 1.9727x; 1.9727x over previous
//
#include <hip/hip_runtime.h>

// Custom LSTM scan.  B=64, L=512, P=64, A=16, D=512, F=80.
//   h_t = h_{t-1} + tanh(x_t W_ci + b_ci) * sigmoid(h_{t-1} R_ig + b_ig)
// One WG (512 thr) per batch row (64 WGs on 256 CUs -> 1 WG/CU).
// Output d computed by 8 lanes (k-slices of 64) reduced via DPP.
// R_ig as f16 pairs, 64 uint4 chunks/thread: 32 pinned in VGPRs
// (launch_bounds(512,1) -> 256-reg cap; (512,2) capped at 128 and spilled),
// 13 in dynamic LDS (104 KB), 19 streamed from L2 per step.
// h broadcast as packed f16 in LDS, bank-swizzled (round-4: conflicts = 0).

#define B_  64
#define L_  512
#define P_  64
#define A_  16
#define D_  512
#define F_  80
#define CI_R 8

#define NLDS 13                       // R chunks resident in LDS
#define SMEM_BYTES (NLDS * D_ * 16 + 1024 + 32 + 2048)

typedef _Float16 half2_t __attribute__((ext_vector_type(2)));

__device__ __forceinline__ float dot2(unsigned int r, unsigned int h, float acc) {
    return __builtin_amdgcn_fdot2(__builtin_bit_cast(half2_t, h),
                                  __builtin_bit_cast(half2_t, r), acc, false);
}
__device__ __forceinline__ float dot4u(uint4 r, uint4 h, float acc) {
    acc = dot2(r.x, h.x, acc);
    acc = dot2(r.y, h.y, acc);
    acc = dot2(r.z, h.z, acc);
    acc = dot2(r.w, h.w, acc);
    return acc;
}
template<int CTRL>
__device__ __forceinline__ float dpp_mov(float v) {
    return __builtin_bit_cast(float, __builtin_amdgcn_update_dpp(
        0, __builtin_bit_cast(int, v), CTRL, 0xF, 0xF, true));
}
// DPP ctrls: quad_perm(1,0,3,2)=0xB1 (xor1), quad_perm(2,3,0,1)=0x4E (xor2),
// row_half_mirror=0x141 (xor7), row_mirror=0x140 (xor15),
// row_bcast15=0x142, row_bcast31=0x143.

// Pack R_ig fp32[k][d] -> f16-pair uint chunks laid out [w][jc][l][q]:
// uint4 (w,jc,l) with j=jc>>3, c=jc&7 holds pairs p = g*32+c*4+{0..3}
// (k=2p,2p+1) of column d = w*64 + (l>>3)*8 + j, where g = l&7.
__global__ __launch_bounds__(256) void prep_kernel(const float* __restrict__ R,
                                                   unsigned int* __restrict__ Rp) {
    int id = blockIdx.x * 256 + threadIdx.x;          // 131072 uints
    int q = id & 3;
    int l = (id >> 2) & 63;
    int c = (id >> 8) & 7;
    int j = (id >> 11) & 7;
    int w = id >> 14;
    int r = l >> 3, g = l & 7;
    int d = w * 64 + r * 8 + j;
    int p = g * 32 + c * 4 + q;
    int k0 = 2 * p;
    half2_t v;
    v.x = (_Float16)R[k0 * D_ + d];
    v.y = (_Float16)R[(k0 + 1) * D_ + d];
    Rp[id] = __builtin_bit_cast(unsigned int, v);
}

// ci = tanh(x @ W_ci + b_ci), stored f16.  One block does CI_R (b,l) rows.
__global__ __launch_bounds__(256) void ci_kernel(const float* __restrict__ obs,
                                                 const float* __restrict__ act,
                                                 const float* __restrict__ W,
                                                 const float* __restrict__ bci,
                                                 unsigned short* __restrict__ ci) {
    __shared__ float xs[CI_R][F_];
    int row0 = blockIdx.x * CI_R;
    int tid = threadIdx.x;
    for (int idx = tid; idx < CI_R * F_; idx += 256) {
        int r = idx / F_, f = idx % F_;
        float v = (f < P_) ? obs[(size_t)(row0 + r) * P_ + f]
                           : act[(size_t)(row0 + r) * A_ + (f - P_)];
        xs[r][f] = v;
    }
    __syncthreads();
    int d0 = tid, d1 = tid + 256;
    float a0[CI_R], a1[CI_R];
    #pragma unroll
    for (int r = 0; r < CI_R; ++r) { a0[r] = 0.f; a1[r] = 0.f; }
    for (int f = 0; f < F_; ++f) {
        float w0 = W[f * D_ + d0];
        float w1 = W[f * D_ + d1];
        #pragma unroll
        for (int r = 0; r < CI_R; ++r) {
            float xv = xs[r][f];
            a0[r] += xv * w0;
            a1[r] += xv * w1;
        }
    }
    float b0 = bci[d0], b1 = bci[d1];
    #pragma unroll
    for (int r = 0; r < CI_R; ++r) {
        float z0 = a0[r] + b0, z1 = a1[r] + b1;
        float e0 = __expf(-2.f * __builtin_fabsf(z0));
        float e1 = __expf(-2.f * __builtin_fabsf(z1));
        float m0 = (1.f - e0) * __builtin_amdgcn_rcpf(1.f + e0);
        float m1 = (1.f - e1) * __builtin_amdgcn_rcpf(1.f + e1);
        float t0 = z0 < 0.f ? -m0 : m0;
        float t1 = z1 < 0.f ? -m1 : m1;
        ci[(size_t)(row0 + r) * D_ + d0] = __builtin_bit_cast(unsigned short, (_Float16)t0);
        ci[(size_t)(row0 + r) * D_ + d1] = __builtin_bit_cast(unsigned short, (_Float16)t1);
    }
}

// Serial scan.  One block per batch row.  Thread (w=tid>>6, l=tid&63):
// g=l&7; computes partials over k in [g*64,g*64+64) for outputs
// d = w*64 + (l>>3)*8 + j, j=0..7; DPP reduce-scatter leaves lane with
// j=g -> thread owns d = tid.  Chunks jc=j*8+c: 0..31 regs (pinned),
// 32..44 LDS, 45..63 streamed from L2 (A=45..53, B=54..63, shared buffer).
__global__ __launch_bounds__(512, 1) void scan_kernel(
    const uint4* __restrict__ Rp, const unsigned short* __restrict__ ci,
    const float* __restrict__ b_ig, const float* __restrict__ W_out,
    const float* __restrict__ b_out, float* __restrict__ out)
{
    const int tid = threadIdx.x;
    const int b = blockIdx.x;
    const int w = tid >> 6;
    const int l = tid & 63;
    const int g = l & 7;

    extern __shared__ __align__(16) char smem[];
    uint4* ldsR = (uint4*)smem;                                   // 13*512*16 B
    unsigned int* hp = (unsigned int*)(smem + NLDS * D_ * 16);    // 1024 B
    float* red = (float*)(smem + NLDS * D_ * 16 + 1024);          // 32 B
    float* outbuf = (float*)(smem + NLDS * D_ * 16 + 1056);       // 2048 B

    const uint4* tb = Rp + (w << 12) + l;   // chunk jc at tb[jc*64]

    // pin 32 chunks (jc 0..31 -> j=0..3) in VGPRs; opaque asm prevents the
    // allocator from sinking the loads back into the t-loop
    uint4 rr[32];
    #pragma unroll
    for (int i = 0; i < 32; ++i) rr[i] = tb[i * 64];
    #pragma unroll
    for (int i = 0; i < 32; ++i)
        asm volatile("" : "+v"(rr[i].x), "+v"(rr[i].y), "+v"(rr[i].z), "+v"(rr[i].w));

    #pragma unroll
    for (int i = 0; i < NLDS; ++i) ldsR[i * D_ + tid] = tb[(32 + i) * 64];
    if (tid < 256) hp[tid] = 0u;

    float hval = 0.f;                      // h[tid], fp32, persistent
    const float bg = b_ig[tid];
    const float wo = W_out[tid];
    const float bo = b_out[0];
    const unsigned short* cip = ci + (size_t)b * L_ * D_ + tid;

    // swizzled h write slot: uint4 index i=tid>>3 has (g_i=w, c_i=(tid>>3)&7);
    // stored at slot (g_i<<3)|((c_i+g_i)&7) so reads are conflict-free
    const int wslot = (((w << 3) | ((((tid >> 3) & 7) + w) & 7)) << 2) | ((tid >> 1) & 3);

    __syncthreads();

    const uint4* hp4s = (const uint4*)hp;

    #pragma unroll 1
    for (int t = 0; t < L_; ++t) {
        // issue stream group A (jc 45..53) + ci load
        uint4 sb[10];
        #pragma unroll
        for (int i = 0; i < 9; ++i) sb[i] = tb[(45 + i) * 64];
        unsigned short cu = cip[t * D_];

        // h slice (8 uint4) from swizzled LDS: slot (g<<3)|((c+g)&7)
        uint4 hsr[8];
        #pragma unroll
        for (int c = 0; c < 8; ++c) hsr[c] = hp4s[(g << 3) | ((c + g) & 7)];

        float p[8];
        #pragma unroll
        for (int j = 0; j < 8; ++j) p[j] = 0.f;

        // register chunks j=0,1 (covers A's L2 latency)
        #pragma unroll
        for (int i = 0; i < 16; ++i) p[i >> 3] = dot4u(rr[i], hsr[i & 7], p[i >> 3]);

        // consume A: jc45..47=(j5,c5..7); jc48..53=(j6,c0..5)
        #pragma unroll
        for (int i = 0; i < 3; ++i) p[5] = dot4u(sb[i], hsr[5 + i], p[5]);
        #pragma unroll
        for (int i = 3; i < 9; ++i) p[6] = dot4u(sb[i], hsr[i - 3], p[6]);

        // issue stream group B (jc 54..63)
        #pragma unroll
        for (int i = 0; i < 10; ++i) sb[i] = tb[(54 + i) * 64];

        // register chunks j=2,3 (covers B's latency)
        #pragma unroll
        for (int i = 16; i < 32; ++i) p[i >> 3] = dot4u(rr[i], hsr[i & 7], p[i >> 3]);

        // LDS chunks: jc32..39=(j4,c0..7) -> p[4]; jc40..44=(j5,c0..4) -> p[5]
        #pragma unroll
        for (int i = 0; i < 8; ++i) p[4] = dot4u(ldsR[i * D_ + tid], hsr[i], p[4]);
        #pragma unroll
        for (int i = 8; i < NLDS; ++i) p[5] = dot4u(ldsR[i * D_ + tid], hsr[i - 8], p[5]);

        // consume B: jc54=(j6,c6), jc55=(j6,c7); jc56..63=(j7,c0..7)
        p[6] = dot4u(sb[0], hsr[6], p[6]);
        p[6] = dot4u(sb[1], hsr[7], p[6]);
        #pragma unroll
        for (int i = 2; i < 10; ++i) p[7] = dot4u(sb[i], hsr[i - 2], p[7]);

        // reduce-scatter over the 8-lane slice group (all DPP):
        float q0[4];
        #pragma unroll
        for (int i = 0; i < 4; ++i) {
            float a = p[i] + dpp_mov<0x141>(p[i]);       // xor7
            float c2 = p[i + 4] + dpp_mov<0x141>(p[i + 4]);
            q0[i] = (g & 4) ? c2 : a;
        }
        float r0a = q0[0] + dpp_mov<0xB1>(q0[0]);        // xor1
        float r0b = q0[1] + dpp_mov<0xB1>(q0[1]);
        float r1a = q0[2] + dpp_mov<0xB1>(q0[2]);
        float r1b = q0[3] + dpp_mov<0xB1>(q0[3]);
        float r0 = (g & 1) ? r0b : r0a;
        float r1 = (g & 1) ? r1b : r1a;
        float za = r0 + dpp_mov<0x4E>(r0);               // xor2
        float zb = r1 + dpp_mov<0x4E>(r1);
        float z = (g & 2) ? zb : za;                     // z for d = tid

        float zz = z + bg;
        float ig = __builtin_amdgcn_rcpf(1.f + __expf(-zz));
        float civ = (float)__builtin_bit_cast(_Float16, cu);
        hval += civ * ig;

        // wave-reduce hval*wo via DPP (sum lands in lane 63)
        float po = hval * wo;
        po += dpp_mov<0xB1>(po);
        po += dpp_mov<0x4E>(po);
        po += dpp_mov<0x141>(po);
        po += dpp_mov<0x140>(po);
        po += dpp_mov<0x142>(po);
        po += dpp_mov<0x143>(po);

        float nbh = dpp_mov<0xB1>(hval);  // neighbor (lane^1) h

        __syncthreads();                  // all reads of old hp complete
        if ((tid & 1) == 0) {
            hp[wslot] = __builtin_bit_cast(unsigned int,
                            __builtin_amdgcn_cvt_pkrtz(hval, nbh));
        }
        if (l == 63) red[w] = po;
        __syncthreads();                  // new hp + partials visible
        if (tid == 0) {
            outbuf[t] = red[0] + red[1] + red[2] + red[3] +
                        red[4] + red[5] + red[6] + red[7] + bo;
        }
    }
    __syncthreads();
    out[b * L_ + tid] = outbuf[tid];
}

extern "C" void kernel_launch(void* const* d_in, const int* in_sizes, int n_in,
                              void* d_out, int out_size, void* d_ws, size_t ws_size,
                              hipStream_t stream) {
    const float* obs   = (const float*)d_in[0];
    const float* act   = (const float*)d_in[1];
    const float* W_ci  = (const float*)d_in[2];
    const float* b_ci  = (const float*)d_in[3];
    const float* R_ig  = (const float*)d_in[4];
    const float* b_ig  = (const float*)d_in[5];
    const float* W_out = (const float*)d_in[6];
    const float* b_out = (const float*)d_in[7];
    float* out = (float*)d_out;

    unsigned short* ci = (unsigned short*)d_ws;                        // 32 MB f16
    unsigned int* Rp = (unsigned int*)((char*)d_ws + (size_t)B_ * L_ * D_ * 2);

    // host-side config (not a stream op; graph-capture safe, idempotent)
    hipFuncSetAttribute((const void*)scan_kernel,
                        hipFuncAttributeMaxDynamicSharedMemorySize, SMEM_BYTES);

    prep_kernel<<<512, 256, 0, stream>>>(R_ig, Rp);
    ci_kernel<<<(B_ * L_) / CI_R, 256, 0, stream>>>(obs, act, W_ci, b_ci, ci);
    scan_kernel<<<B_, D_, SMEM_BYTES, stream>>>((const uint4*)Rp, ci, b_ig, W_out, b_out, out);
}

// Round 6
// 897.765 us; speedup vs baseline: 2.5496x; 1.2925x over previous
//
#include <hip/hip_runtime.h>

// Custom LSTM scan.  B=64, L=512, P=64, A=16, D=512, F=80.
//   h_t = h_{t-1} + tanh(x_t W_ci + b_ci) * sigmoid(h_{t-1} R_ig + b_ig)
// One WG (512 thr) per batch row (64 WGs -> 1 WG/CU).  Output d computed by
// 8 lanes (k-slices of 64) reduced via DPP.  R_ig as f16 pairs, 64 uint4
// chunks/thread: 32 pinned in VGPRs, 16 in dynamic LDS (128 KB), 16 streamed
// from L2 per step.  amdgpu_waves_per_eu(2,2) forces the RA budget to 256
// VGPRs (launch_bounds alone left the scheduler targeting 4 waves/EU -> 128
// regs -> rr spilled to scratch; rounds 1-5 all ran capped at 128).

#define B_  64
#define L_  512
#define P_  64
#define A_  16
#define D_  512
#define F_  80
#define CI_R 8

#define NLDS 16                       // R chunks resident in LDS
#define SMEM_BYTES (NLDS * D_ * 16 + 1024 + 32 + 2048)

typedef _Float16 half2_t __attribute__((ext_vector_type(2)));

__device__ __forceinline__ float dot2(unsigned int r, unsigned int h, float acc) {
    return __builtin_amdgcn_fdot2(__builtin_bit_cast(half2_t, h),
                                  __builtin_bit_cast(half2_t, r), acc, false);
}
__device__ __forceinline__ float dot4u(uint4 r, uint4 h, float acc) {
    acc = dot2(r.x, h.x, acc);
    acc = dot2(r.y, h.y, acc);
    acc = dot2(r.z, h.z, acc);
    acc = dot2(r.w, h.w, acc);
    return acc;
}
template<int CTRL>
__device__ __forceinline__ float dpp_mov(float v) {
    return __builtin_bit_cast(float, __builtin_amdgcn_update_dpp(
        0, __builtin_bit_cast(int, v), CTRL, 0xF, 0xF, true));
}
// DPP ctrls: quad_perm(1,0,3,2)=0xB1 (xor1), quad_perm(2,3,0,1)=0x4E (xor2),
// row_half_mirror=0x141 (xor7), row_mirror=0x140 (xor15),
// row_bcast15=0x142, row_bcast31=0x143.

// Pack R_ig fp32[k][d] -> f16-pair uint chunks laid out [w][jc][l][q]:
// uint4 (w,jc,l) with j=jc>>3, c=jc&7 holds pairs p = g*32+c*4+{0..3}
// (k=2p,2p+1) of column d = w*64 + (l>>3)*8 + j, where g = l&7.
__global__ __launch_bounds__(256) void prep_kernel(const float* __restrict__ R,
                                                   unsigned int* __restrict__ Rp) {
    int id = blockIdx.x * 256 + threadIdx.x;          // 131072 uints
    int q = id & 3;
    int l = (id >> 2) & 63;
    int c = (id >> 8) & 7;
    int j = (id >> 11) & 7;
    int w = id >> 14;
    int r = l >> 3, g = l & 7;
    int d = w * 64 + r * 8 + j;
    int p = g * 32 + c * 4 + q;
    int k0 = 2 * p;
    half2_t v;
    v.x = (_Float16)R[k0 * D_ + d];
    v.y = (_Float16)R[(k0 + 1) * D_ + d];
    Rp[id] = __builtin_bit_cast(unsigned int, v);
}

// ci = tanh(x @ W_ci + b_ci), stored f16.  One block does CI_R (b,l) rows.
__global__ __launch_bounds__(256) void ci_kernel(const float* __restrict__ obs,
                                                 const float* __restrict__ act,
                                                 const float* __restrict__ W,
                                                 const float* __restrict__ bci,
                                                 unsigned short* __restrict__ ci) {
    __shared__ float xs[CI_R][F_];
    int row0 = blockIdx.x * CI_R;
    int tid = threadIdx.x;
    for (int idx = tid; idx < CI_R * F_; idx += 256) {
        int r = idx / F_, f = idx % F_;
        float v = (f < P_) ? obs[(size_t)(row0 + r) * P_ + f]
                           : act[(size_t)(row0 + r) * A_ + (f - P_)];
        xs[r][f] = v;
    }
    __syncthreads();
    int d0 = tid, d1 = tid + 256;
    float a0[CI_R], a1[CI_R];
    #pragma unroll
    for (int r = 0; r < CI_R; ++r) { a0[r] = 0.f; a1[r] = 0.f; }
    for (int f = 0; f < F_; ++f) {
        float w0 = W[f * D_ + d0];
        float w1 = W[f * D_ + d1];
        #pragma unroll
        for (int r = 0; r < CI_R; ++r) {
            float xv = xs[r][f];
            a0[r] += xv * w0;
            a1[r] += xv * w1;
        }
    }
    float b0 = bci[d0], b1 = bci[d1];
    #pragma unroll
    for (int r = 0; r < CI_R; ++r) {
        float z0 = a0[r] + b0, z1 = a1[r] + b1;
        float e0 = __expf(-2.f * __builtin_fabsf(z0));
        float e1 = __expf(-2.f * __builtin_fabsf(z1));
        float m0 = (1.f - e0) * __builtin_amdgcn_rcpf(1.f + e0);
        float m1 = (1.f - e1) * __builtin_amdgcn_rcpf(1.f + e1);
        float t0 = z0 < 0.f ? -m0 : m0;
        float t1 = z1 < 0.f ? -m1 : m1;
        ci[(size_t)(row0 + r) * D_ + d0] = __builtin_bit_cast(unsigned short, (_Float16)t0);
        ci[(size_t)(row0 + r) * D_ + d1] = __builtin_bit_cast(unsigned short, (_Float16)t1);
    }
}

// Serial scan.  One block per batch row.  Thread (w=tid>>6, l=tid&63):
// g=l&7; computes partials over k in [g*64,g*64+64) for outputs
// d = w*64 + (l>>3)*8 + j, j=0..7; DPP reduce-scatter leaves lane with
// j=g -> thread owns d = tid.  Chunks jc=j*8+c: 0..31 regs (pinned),
// 32..47 LDS (j=4,5), 48..55 stream A (j=6), 56..63 stream B (j=7).
__global__ __launch_bounds__(512)
__attribute__((amdgpu_waves_per_eu(2, 2)))
void scan_kernel(
    const uint4* __restrict__ Rp, const unsigned short* __restrict__ ci,
    const float* __restrict__ b_ig, const float* __restrict__ W_out,
    const float* __restrict__ b_out, float* __restrict__ out)
{
    const int tid = threadIdx.x;
    const int b = blockIdx.x;
    const int w = tid >> 6;
    const int l = tid & 63;
    const int g = l & 7;

    extern __shared__ __align__(16) char smem[];
    uint4* ldsR = (uint4*)smem;                                   // 16*512*16 B
    unsigned int* hp = (unsigned int*)(smem + NLDS * D_ * 16);    // 1024 B
    float* red = (float*)(smem + NLDS * D_ * 16 + 1024);          // 32 B
    float* outbuf = (float*)(smem + NLDS * D_ * 16 + 1056);       // 2048 B

    const uint4* tb = Rp + (w << 12) + l;   // chunk jc at tb[jc*64]

    // pin 32 chunks (jc 0..31 -> j=0..3) in VGPRs; opaque asm prevents the
    // allocator from sinking the loads back into the t-loop
    uint4 rr[32];
    #pragma unroll
    for (int i = 0; i < 32; ++i) rr[i] = tb[i * 64];
    #pragma unroll
    for (int i = 0; i < 32; ++i)
        asm volatile("" : "+v"(rr[i].x), "+v"(rr[i].y), "+v"(rr[i].z), "+v"(rr[i].w));

    #pragma unroll
    for (int i = 0; i < NLDS; ++i) ldsR[i * D_ + tid] = tb[(32 + i) * 64];
    if (tid < 256) hp[tid] = 0u;

    float hval = 0.f;                      // h[tid], fp32, persistent
    const float bg = b_ig[tid];
    const float wo = W_out[tid];
    const float bo = b_out[0];
    const unsigned short* cip = ci + (size_t)b * L_ * D_ + tid;

    // swizzled h write slot: uint4 index i=tid>>3 has (g_i=w, c_i=(tid>>3)&7);
    // stored at slot (g_i<<3)|((c_i+g_i)&7) so broadcast reads are conflict-free
    const int wslot = (((w << 3) | ((((tid >> 3) & 7) + w) & 7)) << 2) | ((tid >> 1) & 3);

    __syncthreads();

    const uint4* hp4s = (const uint4*)hp;

    #pragma unroll 1
    for (int t = 0; t < L_; ++t) {
        // issue stream group A (jc 48..55, j=6) + ci load
        uint4 sb[8];
        #pragma unroll
        for (int i = 0; i < 8; ++i) sb[i] = tb[(48 + i) * 64];
        unsigned short cu = cip[t * D_];

        // h slice (8 uint4) from swizzled LDS: slot (g<<3)|((c+g)&7)
        uint4 hsr[8];
        #pragma unroll
        for (int c = 0; c < 8; ++c) hsr[c] = hp4s[(g << 3) | ((c + g) & 7)];

        float p[8];
        #pragma unroll
        for (int j = 0; j < 8; ++j) p[j] = 0.f;

        // register chunks j=0,1 (covers A's L2 latency)
        #pragma unroll
        for (int i = 0; i < 16; ++i) p[i >> 3] = dot4u(rr[i], hsr[i & 7], p[i >> 3]);

        // consume A -> p[6]
        #pragma unroll
        for (int c = 0; c < 8; ++c) p[6] = dot4u(sb[c], hsr[c], p[6]);

        // issue stream group B (jc 56..63, j=7)
        #pragma unroll
        for (int i = 0; i < 8; ++i) sb[i] = tb[(56 + i) * 64];

        // register chunks j=2,3 (covers B's latency)
        #pragma unroll
        for (int i = 16; i < 32; ++i) p[i >> 3] = dot4u(rr[i], hsr[i & 7], p[i >> 3]);

        // LDS chunks: jc32..39=(j4,c0..7) -> p[4]; jc40..47=(j5,c0..7) -> p[5]
        #pragma unroll
        for (int i = 0; i < 8; ++i) p[4] = dot4u(ldsR[i * D_ + tid], hsr[i], p[4]);
        #pragma unroll
        for (int i = 8; i < 16; ++i) p[5] = dot4u(ldsR[i * D_ + tid], hsr[i - 8], p[5]);

        // consume B -> p[7]
        #pragma unroll
        for (int c = 0; c < 8; ++c) p[7] = dot4u(sb[c], hsr[c], p[7]);

        // reduce-scatter over the 8-lane slice group (all DPP):
        float q0[4];
        #pragma unroll
        for (int i = 0; i < 4; ++i) {
            float a = p[i] + dpp_mov<0x141>(p[i]);       // xor7
            float c2 = p[i + 4] + dpp_mov<0x141>(p[i + 4]);
            q0[i] = (g & 4) ? c2 : a;
        }
        float r0a = q0[0] + dpp_mov<0xB1>(q0[0]);        // xor1
        float r0b = q0[1] + dpp_mov<0xB1>(q0[1]);
        float r1a = q0[2] + dpp_mov<0xB1>(q0[2]);
        float r1b = q0[3] + dpp_mov<0xB1>(q0[3]);
        float r0 = (g & 1) ? r0b : r0a;
        float r1 = (g & 1) ? r1b : r1a;
        float za = r0 + dpp_mov<0x4E>(r0);               // xor2
        float zb = r1 + dpp_mov<0x4E>(r1);
        float z = (g & 2) ? zb : za;                     // z for d = tid

        float zz = z + bg;
        float ig = __builtin_amdgcn_rcpf(1.f + __expf(-zz));
        float civ = (float)__builtin_bit_cast(_Float16, cu);
        hval += civ * ig;

        // wave-reduce hval*wo via DPP (sum lands in lane 63)
        float po = hval * wo;
        po += dpp_mov<0xB1>(po);
        po += dpp_mov<0x4E>(po);
        po += dpp_mov<0x141>(po);
        po += dpp_mov<0x140>(po);
        po += dpp_mov<0x142>(po);
        po += dpp_mov<0x143>(po);

        float nbh = dpp_mov<0xB1>(hval);  // neighbor (lane^1) h

        __syncthreads();                  // all reads of old hp complete
        if ((tid & 1) == 0) {
            hp[wslot] = __builtin_bit_cast(unsigned int,
                            __builtin_amdgcn_cvt_pkrtz(hval, nbh));
        }
        if (l == 63) red[w] = po;
        __syncthreads();                  // new hp + partials visible
        if (tid == 0) {
            outbuf[t] = red[0] + red[1] + red[2] + red[3] +
                        red[4] + red[5] + red[6] + red[7] + bo;
        }
    }
    __syncthreads();
    out[b * L_ + tid] = outbuf[tid];
}

extern "C" void kernel_launch(void* const* d_in, const int* in_sizes, int n_in,
                              void* d_out, int out_size, void* d_ws, size_t ws_size,
                              hipStream_t stream) {
    const float* obs   = (const float*)d_in[0];
    const float* act   = (const float*)d_in[1];
    const float* W_ci  = (const float*)d_in[2];
    const float* b_ci  = (const float*)d_in[3];
    const float* R_ig  = (const float*)d_in[4];
    const float* b_ig  = (const float*)d_in[5];
    const float* W_out = (const float*)d_in[6];
    const float* b_out = (const float*)d_in[7];
    float* out = (float*)d_out;

    unsigned short* ci = (unsigned short*)d_ws;                        // 32 MB f16
    unsigned int* Rp = (unsigned int*)((char*)d_ws + (size_t)B_ * L_ * D_ * 2);

    // host-side config (not a stream op; graph-capture safe, idempotent)
    hipFuncSetAttribute((const void*)scan_kernel,
                        hipFuncAttributeMaxDynamicSharedMemorySize, SMEM_BYTES);

    prep_kernel<<<512, 256, 0, stream>>>(R_ig, Rp);
    ci_kernel<<<(B_ * L_) / CI_R, 256, 0, stream>>>(obs, act, W_ci, b_ci, ci);
    scan_kernel<<<B_, D_, SMEM_BYTES, stream>>>((const uint4*)Rp, ci, b_ig, W_out, b_out, out);
}